// Round 8
// baseline (5714.805 us; speedup 1.0000x reference)
//
#include <hip/hip_runtime.h>
#include <math.h>

#define N 1024
#define D 512
#define NIT 200
#define PIT 50

typedef __attribute__((ext_vector_type(8))) short short8;
typedef __attribute__((ext_vector_type(4))) float floatx4;

// ---------------- helpers ----------------
__device__ __forceinline__ float wave_reduce(float v) {
#pragma unroll
  for (int off = 32; off; off >>= 1) v += __shfl_xor(v, off, 64);
  return v;
}
__device__ __forceinline__ unsigned short f2bf(float x) {
  unsigned int u = __float_as_uint(x);
  u += 0x7FFF + ((u >> 16) & 1);  // round-to-nearest-even
  return (unsigned short)(u >> 16);
}
__device__ __forceinline__ float bf2f(unsigned short h) {
  return __uint_as_float(((unsigned int)h) << 16);
}

// async global->LDS, 16 B per lane; LDS dest is wave-uniform base + lane*16
#define GLD16(g, l)                                                     \
  __builtin_amdgcn_global_load_lds(                                     \
      (__attribute__((address_space(1))) void*)(g),                     \
      (__attribute__((address_space(3))) void*)(l), 16, 0, 0)

// ---------------- row normalize ----------------
__global__ __launch_bounds__(256) void normalize_k(
    const float* __restrict__ f1, const float* __restrict__ f2,
    float* __restrict__ Yn, float* __restrict__ An) {
  int b = blockIdx.x;
  const float* src;
  float* dst;
  if (b < N) { src = f1 + (size_t)b * D; dst = Yn + (size_t)b * D; }
  else       { src = f2 + (size_t)(b - N) * D; dst = An + (size_t)(b - N) * D; }
  int tid = threadIdx.x;
  float2 e = ((const float2*)src)[tid];
  float ss = e.x * e.x + e.y * e.y;
  ss = wave_reduce(ss);
  __shared__ float sh[4];
  int lane = tid & 63, wid = tid >> 6;
  if (lane == 0) sh[wid] = ss;
  __syncthreads();
  float total = sh[0] + sh[1] + sh[2] + sh[3];
  float rn = 1.0f / sqrtf(total);
  ((float2*)dst)[tid] = make_float2(e.x * rn, e.y * rn);
}

// ---------------- fp32 NT GEMM (one-time uses: M, YAt, final P) ----------------
#define LDT 68
__global__ __launch_bounds__(256) void gemm_nt(
    const float* __restrict__ A, int lda,
    const float* __restrict__ B, int ldb,
    float* __restrict__ C, int ldc, int K) {
  __shared__ __align__(16) float At[32][LDT];
  __shared__ __align__(16) float Bt[32][LDT];
  const int tid = threadIdx.x;
  const int rowBase = blockIdx.y * 64;
  const int colBase = blockIdx.x * 64;
  const int tx = tid & 15, ty = tid >> 4;
  float acc[4][4] = {};
  const int r0 = tid >> 3;
  const int r1 = r0 + 32;
  const int kc = (tid & 7) * 4;

  for (int k0 = 0; k0 < K; k0 += 32) {
    __syncthreads();
    {
      float4 av = *(const float4*)(A + (size_t)(rowBase + r0) * lda + k0 + kc);
      At[kc + 0][r0] = av.x; At[kc + 1][r0] = av.y; At[kc + 2][r0] = av.z; At[kc + 3][r0] = av.w;
      float4 bv = *(const float4*)(B + (size_t)(colBase + r0) * ldb + k0 + kc);
      Bt[kc + 0][r0] = bv.x; Bt[kc + 1][r0] = bv.y; Bt[kc + 2][r0] = bv.z; Bt[kc + 3][r0] = bv.w;
      av = *(const float4*)(A + (size_t)(rowBase + r1) * lda + k0 + kc);
      At[kc + 0][r1] = av.x; At[kc + 1][r1] = av.y; At[kc + 2][r1] = av.z; At[kc + 3][r1] = av.w;
      bv = *(const float4*)(B + (size_t)(colBase + r1) * ldb + k0 + kc);
      Bt[kc + 0][r1] = bv.x; Bt[kc + 1][r1] = bv.y; Bt[kc + 2][r1] = bv.z; Bt[kc + 3][r1] = bv.w;
    }
    __syncthreads();
#pragma unroll
    for (int kk = 0; kk < 32; ++kk) {
      float4 a4 = *(const float4*)&At[kk][ty * 4];
      float4 b4 = *(const float4*)&Bt[kk][tx * 4];
      float a[4] = {a4.x, a4.y, a4.z, a4.w};
      float b[4] = {b4.x, b4.y, b4.z, b4.w};
#pragma unroll
      for (int r = 0; r < 4; ++r)
#pragma unroll
        for (int c = 0; c < 4; ++c) acc[r][c] = fmaf(a[r], b[c], acc[r][c]);
    }
  }
#pragma unroll
  for (int r = 0; r < 4; ++r) {
    int i = rowBase + ty * 4 + r;
    size_t off = (size_t)i * ldc + colBase + tx * 4;
    *(float4*)(C + off) = make_float4(acc[r][0], acc[r][1], acc[r][2], acc[r][3]);
  }
}

// ---------------- split fp32 -> bf16 hi/lo (row-major, separate arrays) -------
__global__ __launch_bounds__(256) void split_k(const float* __restrict__ Mm,
                                               unsigned short* __restrict__ Mh,
                                               unsigned short* __restrict__ Ml) {
  int i = blockIdx.x * 256 + threadIdx.x;
  float x = Mm[i];
  unsigned short h = f2bf(x);
  Mh[i] = h;
  Ml[i] = f2bf(x - bf2f(h));
}

// ---------------- init: Xa=Xb=1/N fp32, Zq=bf16(1/N), v=1/N -------------------
__global__ __launch_bounds__(256) void init_k(float* __restrict__ Xa,
                                              float* __restrict__ Xb,
                                              unsigned short* __restrict__ Zq,
                                              float* __restrict__ v) {
  int i = blockIdx.x * 256 + threadIdx.x;
  const float c = 1.0f / (float)N;
  Xa[i] = c;
  Xb[i] = c;
  Zq[i] = f2bf(c);  // 2^-10 exact in bf16
  if (i < N) v[i] = c;
}

// ---------------- zero V ----------------
__global__ __launch_bounds__(256) void zeroV_k(float* __restrict__ V) {
  int i = blockIdx.x * 256 + threadIdx.x;
  ((float4*)V)[i] = make_float4(0.f, 0.f, 0.f, 0.f);
}

// ---------------- matvec: w = scale * (M v) ----------------
__global__ __launch_bounds__(256) void matvec_k(
    const float* __restrict__ Mm, const float* __restrict__ v,
    float* __restrict__ w, float scale) {
  int tid = threadIdx.x;
  int lane = tid & 63, wid = tid >> 6;
  int row = blockIdx.x * 4 + wid;
  const float* mr = Mm + (size_t)row * N;
  float s = 0.0f;
#pragma unroll
  for (int j = 0; j < N; j += 64) s = fmaf(mr[j + lane], v[j + lane], s);
  s = wave_reduce(s);
  if (lane == 0) w[row] = s * scale;
}

// ---------------- Rayleigh -> step ----------------
__global__ __launch_bounds__(256) void rayleigh_k(
    const float* __restrict__ u, const float* __restrict__ w,
    float* __restrict__ stepOut) {
  int tid = threadIdx.x;
  float r1 = 0.0f, r2 = 0.0f;
  for (int j = tid; j < N; j += 256) {
    float uu = u[j];
    r1 = fmaf(uu, w[j], r1);
    r2 = fmaf(uu, uu, r2);
  }
  r1 = wave_reduce(r1);
  r2 = wave_reduce(r2);
  __shared__ float sh[8];
  int lane = tid & 63, wid = tid >> 6;
  if (lane == 0) { sh[wid] = r1; sh[4 + wid] = r2; }
  __syncthreads();
  if (tid == 0) {
    float R1 = sh[0] + sh[1] + sh[2] + sh[3];
    float R2 = sh[4] + sh[5] + sh[6] + sh[7];
    stepOut[0] = 1.0f / (2.0f * (R1 / R2) + 1e-8f);
  }
}

// ---------------- FISTA GEMM: 128x64 tile, splitK=4, 2-term split -------------
// acc = Zq*Mh + Zq*Ml (fp32 accumulate); partials atomicAdd into V.
// Grid 512 = 8 rowTiles x 16 colTiles x 4 K-quarters; XCD = b&7 fixes
// (colHalf, kQuarter): per-XCD footprint ~1 MB < 4 MB L2.
__global__ __launch_bounds__(256, 2) void fista_gemm(
    const unsigned short* __restrict__ Zq,
    const unsigned short* __restrict__ Mh, const unsigned short* __restrict__ Ml,
    float* __restrict__ V) {
  __shared__ __align__(16) unsigned short sA[2][128 * 64];   // 32 KB
  __shared__ __align__(16) unsigned short sBh[2][64 * 64];   // 16 KB
  __shared__ __align__(16) unsigned short sBl[2][64 * 64];   // 16 KB
  const int tid = threadIdx.x;
  const int b = blockIdx.x;
  const int kq = (b >> 1) & 3;
  const int jj = b >> 3;
  const int rowBase = (jj & 7) * 128;
  const int colBase = ((b & 1) * 8 + (jj >> 3)) * 64;
  const int kbase = kq * 256;
  const int lane = tid & 63, wv = tid >> 6;
  const int wr = (wv >> 1) * 64, wc = (wv & 1) * 32;  // wave tile 64x32
  const int q = lane >> 4, m = lane & 15;

  floatx4 acc[4][2];
#pragma unroll
  for (int t = 0; t < 4; ++t)
#pragma unroll
    for (int u = 0; u < 2; ++u) acc[t][u] = (floatx4){0.f, 0.f, 0.f, 0.f};

  // staging addresses: LDS slot idx -> global chunk, XOR-8 swizzle on the
  // global side (row = idx>>3, chunk = (idx&7) ^ (row&7)); lane-contiguous LDS.
  size_t gA[4], gB[2];
#pragma unroll
  for (int i = 0; i < 4; ++i) {
    int idx = tid + i * 256;
    int r = idx >> 3, c = (idx & 7) ^ (r & 7);
    gA[i] = (size_t)(rowBase + r) * N + c * 8 + kbase;
  }
#pragma unroll
  for (int i = 0; i < 2; ++i) {
    int idx = tid + i * 256;
    int r = idx >> 3, c = (idx & 7) ^ (r & 7);
    gB[i] = (size_t)(colBase + r) * N + c * 8 + kbase;
  }

#define ISSUE(buf, ko)                                       \
  do {                                                       \
    GLD16(Zq + gA[0] + (ko), &sA[buf][tid * 8]);             \
    GLD16(Zq + gA[1] + (ko), &sA[buf][(tid + 256) * 8]);     \
    GLD16(Zq + gA[2] + (ko), &sA[buf][(tid + 512) * 8]);     \
    GLD16(Zq + gA[3] + (ko), &sA[buf][(tid + 768) * 8]);     \
    GLD16(Mh + gB[0] + (ko), &sBh[buf][tid * 8]);            \
    GLD16(Mh + gB[1] + (ko), &sBh[buf][(tid + 256) * 8]);    \
    GLD16(Ml + gB[0] + (ko), &sBl[buf][tid * 8]);            \
    GLD16(Ml + gB[1] + (ko), &sBl[buf][(tid + 256) * 8]);    \
  } while (0)

  ISSUE(0, 0);
  __syncthreads();
  for (int kt = 0; kt < 4; ++kt) {  // K=256 per block, BK=64
    const int cur = kt & 1;
    if (kt + 1 < 4) ISSUE(cur ^ 1, (kt + 1) * 64);
#pragma unroll
    for (int s = 0; s < 2; ++s) {
      short8 a[4], bh[2], bl[2];
#pragma unroll
      for (int t = 0; t < 4; ++t) {
        int ar = wr + t * 16 + m;
        a[t] = *(const short8*)&sA[cur][ar * 64 + (((s * 4 + q) ^ (ar & 7)) * 8)];
      }
#pragma unroll
      for (int u = 0; u < 2; ++u) {
        int br = wc + u * 16 + m;
        int off = br * 64 + (((s * 4 + q) ^ (br & 7)) * 8);
        bh[u] = *(const short8*)&sBh[cur][off];
        bl[u] = *(const short8*)&sBl[cur][off];
      }
#pragma unroll
      for (int t = 0; t < 4; ++t)
#pragma unroll
        for (int u = 0; u < 2; ++u) {
          acc[t][u] = __builtin_amdgcn_mfma_f32_16x16x32_bf16(a[t], bh[u], acc[t][u], 0, 0, 0);
          acc[t][u] = __builtin_amdgcn_mfma_f32_16x16x32_bf16(a[t], bl[u], acc[t][u], 0, 0, 0);
        }
    }
    __syncthreads();
  }
#undef ISSUE

  // epilogue: C/D layout col = lane&15, row = (lane>>4)*4 + reg; 4 K-quarter
  // blocks accumulate the same tile via device-scope fp32 atomics.
#pragma unroll
  for (int t = 0; t < 4; ++t) {
    int rowb = rowBase + wr + t * 16 + q * 4;
#pragma unroll
    for (int u = 0; u < 2; ++u) {
      int col = colBase + wc + u * 16 + m;
#pragma unroll
      for (int r = 0; r < 4; ++r)
        atomicAdd(&V[(size_t)(rowb + r) * N + col], acc[t][u][r]);
    }
  }
}

// ---------------- update: exact fp32 Z from ping-pong X + projection ----------
// z = Xcur + momPrev*(Xcur - Xprev)   (exact fp32; only the GRADIENT used Zq)
// v = z - c2*(V - YAt); X_{t+1} = proj(v) -> written into Xnext (ping-pong);
// Zq_{t+1} = bf16(X_{t+1} + momCur*(X_{t+1} - Xcur)); V re-zeroed for next iter.
__global__ __launch_bounds__(256) void fista_update(
    float* __restrict__ V, const float* __restrict__ YAt,
    const float* __restrict__ stepPtr,
    const float* __restrict__ Xcur, float* __restrict__ Xnext,
    unsigned short* __restrict__ Zq, float momPrev, float momCur) {
  __shared__ float sh[8];
  const int r = blockIdx.x, tid = threadIdx.x;
  const int lane = tid & 63, wid = tid >> 6;
  const float c2 = 2.0f * stepPtr[0];
  float4 av = ((const float4*)(V + (size_t)r * N))[tid];
  float4 ya = ((const float4*)(YAt + (size_t)r * N))[tid];
  float4 xc = ((const float4*)(Xcur + (size_t)r * N))[tid];
  float4 xp = ((const float4*)(Xnext + (size_t)r * N))[tid];
  ((float4*)(V + (size_t)r * N))[tid] = make_float4(0.f, 0.f, 0.f, 0.f);
  float vl[4];
  vl[0] = xc.x + momPrev * (xc.x - xp.x) - c2 * (av.x - ya.x);
  vl[1] = xc.y + momPrev * (xc.y - xp.y) - c2 * (av.y - ya.y);
  vl[2] = xc.z + momPrev * (xc.z - xp.z) - c2 * (av.z - ya.z);
  vl[3] = xc.w + momPrev * (xc.w - xp.w) - c2 * (av.w - ya.w);

  float s = vl[0] + vl[1] + vl[2] + vl[3];
  s = wave_reduce(s);
  if (lane == 0) sh[wid] = s;
  __syncthreads();
  float theta = (sh[0] + sh[1] + sh[2] + sh[3] - 1.0f) * (1.0f / (float)N);
  for (int it = 0; it < 40; ++it) {  // Michelot fixed point (exact projection)
    float sa = 0.0f, ka = 0.0f;
#pragma unroll
    for (int j = 0; j < 4; ++j)
      if (vl[j] > theta) { sa += vl[j]; ka += 1.0f; }
    sa = wave_reduce(sa);
    ka = wave_reduce(ka);
    __syncthreads();
    if (lane == 0) { sh[wid] = sa; sh[4 + wid] = ka; }
    __syncthreads();
    float SA = sh[0] + sh[1] + sh[2] + sh[3];
    float KA = fmaxf(sh[4] + sh[5] + sh[6] + sh[7], 1.0f);
    float tn = (SA - 1.0f) / KA;
    bool done = (tn - theta) <= (1e-7f * fabsf(tn) + 1e-12f);  // block-uniform
    theta = tn;
    if (done) break;
  }
  float xn[4], zn[4];
  float xcur[4] = {xc.x, xc.y, xc.z, xc.w};
#pragma unroll
  for (int j = 0; j < 4; ++j) {
    xn[j] = fmaxf(vl[j] - theta, 0.0f);
    zn[j] = xn[j] + momCur * (xn[j] - xcur[j]);
  }
  ((float4*)(Xnext + (size_t)r * N))[tid] = make_float4(xn[0], xn[1], xn[2], xn[3]);
  ushort4 zq4;
  zq4.x = f2bf(zn[0]);
  zq4.y = f2bf(zn[1]);
  zq4.z = f2bf(zn[2]);
  zq4.w = f2bf(zn[3]);
  ((ushort4*)(Zq + (size_t)r * N))[tid] = zq4;
}

// ---------------- transpose An [N x D] -> AnT [D x N] ----------------
__global__ void transpose_k(const float* __restrict__ An, float* __restrict__ AnT) {
  __shared__ float t[32][33];
  int x = blockIdx.x * 32 + threadIdx.x;
  int y0 = blockIdx.y * 32;
#pragma unroll
  for (int j = 0; j < 32; j += 8)
    t[threadIdx.y + j][threadIdx.x] = An[(size_t)(y0 + threadIdx.y + j) * D + x];
  __syncthreads();
  int xo = y0 + threadIdx.x;
  int yo0 = blockIdx.x * 32;
#pragma unroll
  for (int j = 0; j < 32; j += 8)
    AnT[(size_t)(yo0 + threadIdx.y + j) * N + xo] = t[threadIdx.x][threadIdx.y + j];
}

// ---------------- per-row cosine ----------------
__global__ __launch_bounds__(128) void cos_k(const float* __restrict__ P,
                                             const float* __restrict__ Yn,
                                             float* __restrict__ cb) {
  int r = blockIdx.x, tid = threadIdx.x;
  float4 p = ((const float4*)(P + (size_t)r * D))[tid];
  float4 y = ((const float4*)(Yn + (size_t)r * D))[tid];
  float d  = p.x * y.x + p.y * y.y + p.z * y.z + p.w * y.w;
  float np = p.x * p.x + p.y * p.y + p.z * p.z + p.w * p.w;
  float ny = y.x * y.x + y.y * y.y + y.z * y.z + y.w * y.w;
  d = wave_reduce(d);
  np = wave_reduce(np);
  ny = wave_reduce(ny);
  __shared__ float sh[6];
  int lane = tid & 63, wid = tid >> 6;
  if (lane == 0) { sh[wid] = d; sh[2 + wid] = np; sh[4 + wid] = ny; }
  __syncthreads();
  if (tid == 0) {
    float dt = sh[0] + sh[1], npt = sh[2] + sh[3], nyt = sh[4] + sh[5];
    cb[r] = dt / (fmaxf(sqrtf(npt), 1e-8f) * fmaxf(sqrtf(nyt), 1e-8f));
  }
}

// ---------------- mean ----------------
__global__ __launch_bounds__(256) void mean_k(const float* __restrict__ cb,
                                              float* __restrict__ out) {
  int tid = threadIdx.x;
  float s = cb[tid] + cb[tid + 256] + cb[tid + 512] + cb[tid + 768];
  s = wave_reduce(s);
  __shared__ float sh[4];
  int lane = tid & 63, wid = tid >> 6;
  if (lane == 0) sh[wid] = s;
  __syncthreads();
  if (tid == 0) out[0] = (sh[0] + sh[1] + sh[2] + sh[3]) * (1.0f / (float)N);
}

// ---------------- host orchestration ----------------
extern "C" void kernel_launch(void* const* d_in, const int* in_sizes, int n_in,
                              void* d_out, int out_size, void* d_ws, size_t ws_size,
                              hipStream_t stream) {
  const float* fea1 = (const float*)d_in[0];
  const float* fea2 = (const float*)d_in[1];
  float* ws = (float*)d_ws;
  // layout (floats), peak ~26 MB:
  float* Yn  = ws;                              // N*D
  float* An  = Yn + (size_t)N * D;              // N*D
  float* Mm  = An + (size_t)N * D;              // N*N (dead after power -> V)
  float* YAt = Mm + (size_t)N * N;              // N*N (dead after loop -> cosb)
  float* Xa  = YAt + (size_t)N * N;             // N*N fp32 ping
  float* Xb  = Xa + (size_t)N * N;              // N*N fp32 pong
  unsigned short* Zq = (unsigned short*)(Xb + (size_t)N * N);  // N*N bf16
  unsigned short* Mh = Zq + (size_t)N * N;
  unsigned short* Ml = Mh + (size_t)N * N;
  float* vb    = (float*)(Ml + (size_t)N * N);  // 3*N
  float* stepP = vb + 3 * N;
  float* V = Mm;                        // alias: Mm dead after power phase
  float* AnT = Mm;                      // alias after FISTA loop (D*N)
  float* P   = Mm + (size_t)N * D;      // alias after FISTA loop (N*D)
  float* cosb = YAt;                    // alias after FISTA loop

  normalize_k<<<2 * N, 256, 0, stream>>>(fea1, fea2, Yn, An);
  gemm_nt<<<dim3(N / 64, N / 64), 256, 0, stream>>>(An, D, An, D, Mm, N, D);
  gemm_nt<<<dim3(N / 64, N / 64), 256, 0, stream>>>(Yn, D, An, D, YAt, N, D);
  split_k<<<(N * N) / 256, 256, 0, stream>>>(Mm, Mh, Ml);
  init_k<<<(N * N) / 256, 256, 0, stream>>>(Xa, Xb, Zq, vb);

  // power iteration (normalization folded into 1/8 scale; lambda_max ~5.8 < 8)
  float* pv = vb;
  float* pw = vb + N;
  for (int i = 0; i < PIT; ++i) {
    matvec_k<<<N / 4, 256, 0, stream>>>(Mm, pv, pw, 0.125f);
    float* t = pv; pv = pw; pw = t;
  }
  matvec_k<<<N / 4, 256, 0, stream>>>(Mm, pv, pw, 1.0f);
  rayleigh_k<<<1, 256, 0, stream>>>(pv, pw, stepP);
  zeroV_k<<<(N * N) / 1024, 256, 0, stream>>>(V);  // Mm dead from here

  float t = 1.0f, momPrev = 0.0f;
  float* Xcur = Xa;
  float* Xnext = Xb;
  for (int it = 0; it < NIT; ++it) {
    fista_gemm<<<512, 256, 0, stream>>>(Zq, Mh, Ml, V);
    float tn = 0.5f * (1.0f + sqrtf(1.0f + 4.0f * t * t));
    float momCur = (t - 1.0f) / tn;
    t = tn;
    fista_update<<<N, 256, 0, stream>>>(V, YAt, stepP, Xcur, Xnext, Zq,
                                        momPrev, momCur);
    momPrev = momCur;
    float* tmp = Xcur; Xcur = Xnext; Xnext = tmp;
  }
  // final X is in Xcur

  transpose_k<<<dim3(D / 32, N / 32), dim3(32, 8), 0, stream>>>(An, AnT);
  gemm_nt<<<dim3(D / 64, N / 64), 256, 0, stream>>>(Xcur, N, AnT, N, P, D, N);
  cos_k<<<N, 128, 0, stream>>>(P, Yn, cosb);
  mean_k<<<1, 256, 0, stream>>>(cosb, (float*)d_out);
}

// Round 9
// 4909.613 us; speedup vs baseline: 1.1640x; 1.1640x over previous
//
#include <hip/hip_runtime.h>
#include <math.h>

#define N 1024
#define D 512
#define NIT 200
#define PIT 50

typedef __attribute__((ext_vector_type(8))) short short8;
typedef __attribute__((ext_vector_type(4))) float floatx4;

// ---------------- helpers ----------------
__device__ __forceinline__ float wave_reduce(float v) {
#pragma unroll
  for (int off = 32; off; off >>= 1) v += __shfl_xor(v, off, 64);
  return v;
}
__device__ __forceinline__ unsigned short f2bf(float x) {
  unsigned int u = __float_as_uint(x);
  u += 0x7FFF + ((u >> 16) & 1);  // round-to-nearest-even
  return (unsigned short)(u >> 16);
}
__device__ __forceinline__ float bf2f(unsigned short h) {
  return __uint_as_float(((unsigned int)h) << 16);
}

// async global->LDS, 16 B per lane; LDS dest is wave-uniform base + lane*16
#define GLD16(g, l)                                                     \
  __builtin_amdgcn_global_load_lds(                                     \
      (__attribute__((address_space(1))) void*)(g),                     \
      (__attribute__((address_space(3))) void*)(l), 16, 0, 0)

// ---------------- row normalize ----------------
__global__ __launch_bounds__(256) void normalize_k(
    const float* __restrict__ f1, const float* __restrict__ f2,
    float* __restrict__ Yn, float* __restrict__ An) {
  int b = blockIdx.x;
  const float* src;
  float* dst;
  if (b < N) { src = f1 + (size_t)b * D; dst = Yn + (size_t)b * D; }
  else       { src = f2 + (size_t)(b - N) * D; dst = An + (size_t)(b - N) * D; }
  int tid = threadIdx.x;
  float2 e = ((const float2*)src)[tid];
  float ss = e.x * e.x + e.y * e.y;
  ss = wave_reduce(ss);
  __shared__ float sh[4];
  int lane = tid & 63, wid = tid >> 6;
  if (lane == 0) sh[wid] = ss;
  __syncthreads();
  float total = sh[0] + sh[1] + sh[2] + sh[3];
  float rn = 1.0f / sqrtf(total);
  ((float2*)dst)[tid] = make_float2(e.x * rn, e.y * rn);
}

// ---------------- fp32 NT GEMM (one-time uses: M, YAt, final P) ----------------
#define LDT 68
__global__ __launch_bounds__(256) void gemm_nt(
    const float* __restrict__ A, int lda,
    const float* __restrict__ B, int ldb,
    float* __restrict__ C, int ldc, int K) {
  __shared__ __align__(16) float At[32][LDT];
  __shared__ __align__(16) float Bt[32][LDT];
  const int tid = threadIdx.x;
  const int rowBase = blockIdx.y * 64;
  const int colBase = blockIdx.x * 64;
  const int tx = tid & 15, ty = tid >> 4;
  float acc[4][4] = {};
  const int r0 = tid >> 3;
  const int r1 = r0 + 32;
  const int kc = (tid & 7) * 4;

  for (int k0 = 0; k0 < K; k0 += 32) {
    __syncthreads();
    {
      float4 av = *(const float4*)(A + (size_t)(rowBase + r0) * lda + k0 + kc);
      At[kc + 0][r0] = av.x; At[kc + 1][r0] = av.y; At[kc + 2][r0] = av.z; At[kc + 3][r0] = av.w;
      float4 bv = *(const float4*)(B + (size_t)(colBase + r0) * ldb + k0 + kc);
      Bt[kc + 0][r0] = bv.x; Bt[kc + 1][r0] = bv.y; Bt[kc + 2][r0] = bv.z; Bt[kc + 3][r0] = bv.w;
      av = *(const float4*)(A + (size_t)(rowBase + r1) * lda + k0 + kc);
      At[kc + 0][r1] = av.x; At[kc + 1][r1] = av.y; At[kc + 2][r1] = av.z; At[kc + 3][r1] = av.w;
      bv = *(const float4*)(B + (size_t)(colBase + r1) * ldb + k0 + kc);
      Bt[kc + 0][r1] = bv.x; Bt[kc + 1][r1] = bv.y; Bt[kc + 2][r1] = bv.z; Bt[kc + 3][r1] = bv.w;
    }
    __syncthreads();
#pragma unroll
    for (int kk = 0; kk < 32; ++kk) {
      float4 a4 = *(const float4*)&At[kk][ty * 4];
      float4 b4 = *(const float4*)&Bt[kk][tx * 4];
      float a[4] = {a4.x, a4.y, a4.z, a4.w};
      float b[4] = {b4.x, b4.y, b4.z, b4.w};
#pragma unroll
      for (int r = 0; r < 4; ++r)
#pragma unroll
        for (int c = 0; c < 4; ++c) acc[r][c] = fmaf(a[r], b[c], acc[r][c]);
    }
  }
#pragma unroll
  for (int r = 0; r < 4; ++r) {
    int i = rowBase + ty * 4 + r;
    size_t off = (size_t)i * ldc + colBase + tx * 4;
    *(float4*)(C + off) = make_float4(acc[r][0], acc[r][1], acc[r][2], acc[r][3]);
  }
}

// ---------------- split fp32 -> bf16 hi/lo ----------------
__global__ __launch_bounds__(256) void split_k(const float* __restrict__ Mm,
                                               unsigned short* __restrict__ Mh,
                                               unsigned short* __restrict__ Ml) {
  int i = blockIdx.x * 256 + threadIdx.x;
  float x = Mm[i];
  unsigned short h = f2bf(x);
  Mh[i] = h;
  Ml[i] = f2bf(x - bf2f(h));
}

// ---------------- init: Xa=Xb=1/N fp32, Zq=bf16(1/N), v=1/N -------------------
__global__ __launch_bounds__(256) void init_k(float* __restrict__ Xa,
                                              float* __restrict__ Xb,
                                              unsigned short* __restrict__ Zq,
                                              float* __restrict__ v) {
  int i = blockIdx.x * 256 + threadIdx.x;
  const float c = 1.0f / (float)N;
  Xa[i] = c;
  Xb[i] = c;
  Zq[i] = f2bf(c);  // 2^-10 exact in bf16
  if (i < N) v[i] = c;
}

// ---------------- matvec: w = scale * (M v) ----------------
__global__ __launch_bounds__(256) void matvec_k(
    const float* __restrict__ Mm, const float* __restrict__ v,
    float* __restrict__ w, float scale) {
  int tid = threadIdx.x;
  int lane = tid & 63, wid = tid >> 6;
  int row = blockIdx.x * 4 + wid;
  const float* mr = Mm + (size_t)row * N;
  float s = 0.0f;
#pragma unroll
  for (int j = 0; j < N; j += 64) s = fmaf(mr[j + lane], v[j + lane], s);
  s = wave_reduce(s);
  if (lane == 0) w[row] = s * scale;
}

// ---------------- Rayleigh -> step ----------------
__global__ __launch_bounds__(256) void rayleigh_k(
    const float* __restrict__ u, const float* __restrict__ w,
    float* __restrict__ stepOut) {
  int tid = threadIdx.x;
  float r1 = 0.0f, r2 = 0.0f;
  for (int j = tid; j < N; j += 256) {
    float uu = u[j];
    r1 = fmaf(uu, w[j], r1);
    r2 = fmaf(uu, uu, r2);
  }
  r1 = wave_reduce(r1);
  r2 = wave_reduce(r2);
  __shared__ float sh[8];
  int lane = tid & 63, wid = tid >> 6;
  if (lane == 0) { sh[wid] = r1; sh[4 + wid] = r2; }
  __syncthreads();
  if (tid == 0) {
    float R1 = sh[0] + sh[1] + sh[2] + sh[3];
    float R2 = sh[4] + sh[5] + sh[6] + sh[7];
    stepOut[0] = 1.0f / (2.0f * (R1 / R2) + 1e-8f);
  }
}

// ---------------- FISTA GEMM: 64x64 tile, BK=32 dbuf, splitK=4 ----------------
// 2-term: acc = Zq*Mh + Zq*Ml (fp32 accumulate). 24 KB LDS -> 4+ blocks/CU.
// Grid 1024 = 16 rowTiles x 16 colTiles x 4 K-quarters; XCD (b&7) fixes
// (kQuarter-pair, colHalf): ~1 MB/XCD footprint. Partials to Vp[kq] (no atomics).
__global__ __launch_bounds__(256, 4) void fista_gemm(
    const unsigned short* __restrict__ Zq,
    const unsigned short* __restrict__ Mh, const unsigned short* __restrict__ Ml,
    float* __restrict__ Vp0, float* __restrict__ Vp1,
    float* __restrict__ Vp2, float* __restrict__ Vp3) {
  __shared__ __align__(16) unsigned short sA[2][2048];   // 4 KB each buf
  __shared__ __align__(16) unsigned short sBh[2][2048];
  __shared__ __align__(16) unsigned short sBl[2][2048];
  const int tid = threadIdx.x;
  const int b = blockIdx.x;
  // XCD-aware decomposition: xcd = b&7 -> kq pair + col half
  const int xcd = b & 7;
  const int j = b >> 3;              // 0..127
  const int kq = (xcd >> 1) & 3;     // K-quarter
  const int colTile = (xcd & 1) * 8 + (j & 7);
  const int rowTile = j >> 3;        // 0..15
  const int rowBase = rowTile * 64;
  const int colBase = colTile * 64;
  const int kbase = kq * 256;
  const int lane = tid & 63, wv = tid >> 6;
  const int wr = (wv >> 1) * 32, wc = (wv & 1) * 32;
  const int q = lane >> 4, m = lane & 15;

  floatx4 acc[2][2];
#pragma unroll
  for (int t = 0; t < 2; ++t)
#pragma unroll
    for (int u = 0; u < 2; ++u) acc[t][u] = (floatx4){0.f, 0.f, 0.f, 0.f};

  // staging: 256 slots of 16B = 64 rows x 4 chunks; XOR-4 swizzle on global side
  const int sr = tid >> 2;
  const int cg = (tid & 3) ^ (sr & 3);
  const size_t ga = (size_t)(rowBase + sr) * N + cg * 8 + kbase;
  const size_t gb = (size_t)(colBase + sr) * N + cg * 8 + kbase;

#define ISSUE(buf, ko)                                \
  do {                                                \
    GLD16(Zq + ga + (ko), &sA[buf][tid * 8]);         \
    GLD16(Mh + gb + (ko), &sBh[buf][tid * 8]);        \
    GLD16(Ml + gb + (ko), &sBl[buf][tid * 8]);        \
  } while (0)

  ISSUE(0, 0);
  __syncthreads();
  for (int kt = 0; kt < 8; ++kt) {  // 8 k-tiles of 32 (K=256 per block)
    const int cur = kt & 1;
    if (kt + 1 < 8) ISSUE(cur ^ 1, (kt + 1) * 32);
    short8 a[2], bh[2], bl[2];
#pragma unroll
    for (int t = 0; t < 2; ++t) {
      int ar = wr + t * 16 + m;
      a[t] = *(const short8*)&sA[cur][ar * 32 + ((q ^ (ar & 3)) * 8)];
    }
#pragma unroll
    for (int u = 0; u < 2; ++u) {
      int br = wc + u * 16 + m;
      int off = br * 32 + ((q ^ (br & 3)) * 8);
      bh[u] = *(const short8*)&sBh[cur][off];
      bl[u] = *(const short8*)&sBl[cur][off];
    }
#pragma unroll
    for (int t = 0; t < 2; ++t)
#pragma unroll
      for (int u = 0; u < 2; ++u) {
        acc[t][u] = __builtin_amdgcn_mfma_f32_16x16x32_bf16(a[t], bh[u], acc[t][u], 0, 0, 0);
        acc[t][u] = __builtin_amdgcn_mfma_f32_16x16x32_bf16(a[t], bl[u], acc[t][u], 0, 0, 0);
      }
    __syncthreads();
  }
#undef ISSUE

  float* out = (kq == 0) ? Vp0 : (kq == 1) ? Vp1 : (kq == 2) ? Vp2 : Vp3;
  // C/D layout: col = lane&15, row = (lane>>4)*4 + reg
#pragma unroll
  for (int t = 0; t < 2; ++t) {
    int rowb = rowBase + wr + t * 16 + q * 4;
#pragma unroll
    for (int u = 0; u < 2; ++u) {
      int col = colBase + wc + u * 16 + m;
#pragma unroll
      for (int r = 0; r < 4; ++r)
        out[(size_t)(rowb + r) * N + col] = acc[t][u][r];
    }
  }
}

// ---------------- update: exact fp32 Z from ping-pong X + projection ----------
// z = Xcur + momPrev*(Xcur - Xprev); v = z - c2*(SUM Vp - YAt);
// Xnext = proj(v); Zq = bf16(Xnext + momCur*(Xnext - Xcur)).
__global__ __launch_bounds__(256) void fista_update(
    const float* __restrict__ Vp0, const float* __restrict__ Vp1,
    const float* __restrict__ Vp2, const float* __restrict__ Vp3,
    const float* __restrict__ YAt, const float* __restrict__ stepPtr,
    const float* __restrict__ Xcur, float* __restrict__ Xnext,
    unsigned short* __restrict__ Zq, float momPrev, float momCur) {
  __shared__ float sh[8];
  const int r = blockIdx.x, tid = threadIdx.x;
  const int lane = tid & 63, wid = tid >> 6;
  const float c2 = 2.0f * stepPtr[0];
  float4 a0 = ((const float4*)(Vp0 + (size_t)r * N))[tid];
  float4 a1 = ((const float4*)(Vp1 + (size_t)r * N))[tid];
  float4 a2 = ((const float4*)(Vp2 + (size_t)r * N))[tid];
  float4 a3 = ((const float4*)(Vp3 + (size_t)r * N))[tid];
  float4 ya = ((const float4*)(YAt + (size_t)r * N))[tid];
  float4 xc = ((const float4*)(Xcur + (size_t)r * N))[tid];
  float4 xp = ((const float4*)(Xnext + (size_t)r * N))[tid];
  float vl[4];
  vl[0] = xc.x + momPrev * (xc.x - xp.x) - c2 * (a0.x + a1.x + a2.x + a3.x - ya.x);
  vl[1] = xc.y + momPrev * (xc.y - xp.y) - c2 * (a0.y + a1.y + a2.y + a3.y - ya.y);
  vl[2] = xc.z + momPrev * (xc.z - xp.z) - c2 * (a0.z + a1.z + a2.z + a3.z - ya.z);
  vl[3] = xc.w + momPrev * (xc.w - xp.w) - c2 * (a0.w + a1.w + a2.w + a3.w - ya.w);

  float s = vl[0] + vl[1] + vl[2] + vl[3];
  s = wave_reduce(s);
  if (lane == 0) sh[wid] = s;
  __syncthreads();
  float theta = (sh[0] + sh[1] + sh[2] + sh[3] - 1.0f) * (1.0f / (float)N);
  for (int it = 0; it < 40; ++it) {  // Michelot fixed point (exact projection)
    float sa = 0.0f, ka = 0.0f;
#pragma unroll
    for (int j = 0; j < 4; ++j)
      if (vl[j] > theta) { sa += vl[j]; ka += 1.0f; }
    sa = wave_reduce(sa);
    ka = wave_reduce(ka);
    __syncthreads();
    if (lane == 0) { sh[wid] = sa; sh[4 + wid] = ka; }
    __syncthreads();
    float SA = sh[0] + sh[1] + sh[2] + sh[3];
    float KA = fmaxf(sh[4] + sh[5] + sh[6] + sh[7], 1.0f);
    float tn = (SA - 1.0f) / KA;
    bool done = (tn - theta) <= (1e-7f * fabsf(tn) + 1e-12f);  // block-uniform
    theta = tn;
    if (done) break;
  }
  float xn[4], zn[4];
  float xcur[4] = {xc.x, xc.y, xc.z, xc.w};
#pragma unroll
  for (int j = 0; j < 4; ++j) {
    xn[j] = fmaxf(vl[j] - theta, 0.0f);
    zn[j] = xn[j] + momCur * (xn[j] - xcur[j]);
  }
  ((float4*)(Xnext + (size_t)r * N))[tid] = make_float4(xn[0], xn[1], xn[2], xn[3]);
  ushort4 zq4;
  zq4.x = f2bf(zn[0]);
  zq4.y = f2bf(zn[1]);
  zq4.z = f2bf(zn[2]);
  zq4.w = f2bf(zn[3]);
  ((ushort4*)(Zq + (size_t)r * N))[tid] = zq4;
}

// ---------------- transpose An [N x D] -> AnT [D x N] ----------------
__global__ void transpose_k(const float* __restrict__ An, float* __restrict__ AnT) {
  __shared__ float t[32][33];
  int x = blockIdx.x * 32 + threadIdx.x;
  int y0 = blockIdx.y * 32;
#pragma unroll
  for (int j = 0; j < 32; j += 8)
    t[threadIdx.y + j][threadIdx.x] = An[(size_t)(y0 + threadIdx.y + j) * D + x];
  __syncthreads();
  int xo = y0 + threadIdx.x;
  int yo0 = blockIdx.x * 32;
#pragma unroll
  for (int j = 0; j < 32; j += 8)
    AnT[(size_t)(yo0 + threadIdx.y + j) * N + xo] = t[threadIdx.x][threadIdx.y + j];
}

// ---------------- per-row cosine ----------------
__global__ __launch_bounds__(128) void cos_k(const float* __restrict__ P,
                                             const float* __restrict__ Yn,
                                             float* __restrict__ cb) {
  int r = blockIdx.x, tid = threadIdx.x;
  float4 p = ((const float4*)(P + (size_t)r * D))[tid];
  float4 y = ((const float4*)(Yn + (size_t)r * D))[tid];
  float d  = p.x * y.x + p.y * y.y + p.z * y.z + p.w * y.w;
  float np = p.x * p.x + p.y * p.y + p.z * p.z + p.w * p.w;
  float ny = y.x * y.x + y.y * y.y + y.z * y.z + y.w * y.w;
  d = wave_reduce(d);
  np = wave_reduce(np);
  ny = wave_reduce(ny);
  __shared__ float sh[6];
  int lane = tid & 63, wid = tid >> 6;
  if (lane == 0) { sh[wid] = d; sh[2 + wid] = np; sh[4 + wid] = ny; }
  __syncthreads();
  if (tid == 0) {
    float dt = sh[0] + sh[1], npt = sh[2] + sh[3], nyt = sh[4] + sh[5];
    cb[r] = dt / (fmaxf(sqrtf(npt), 1e-8f) * fmaxf(sqrtf(nyt), 1e-8f));
  }
}

// ---------------- mean ----------------
__global__ __launch_bounds__(256) void mean_k(const float* __restrict__ cb,
                                              float* __restrict__ out) {
  int tid = threadIdx.x;
  float s = cb[tid] + cb[tid + 256] + cb[tid + 512] + cb[tid + 768];
  s = wave_reduce(s);
  __shared__ float sh[4];
  int lane = tid & 63, wid = tid >> 6;
  if (lane == 0) sh[wid] = s;
  __syncthreads();
  if (tid == 0) out[0] = (sh[0] + sh[1] + sh[2] + sh[3]) * (1.0f / (float)N);
}

// ---------------- host orchestration ----------------
extern "C" void kernel_launch(void* const* d_in, const int* in_sizes, int n_in,
                              void* d_out, int out_size, void* d_ws, size_t ws_size,
                              hipStream_t stream) {
  const float* fea1 = (const float*)d_in[0];
  const float* fea2 = (const float*)d_in[1];
  float* ws = (float*)d_ws;
  // layout (floats), ~38 MB peak:
  float* Yn  = ws;                              // N*D
  float* An  = Yn + (size_t)N * D;              // N*D
  float* Mm  = An + (size_t)N * D;              // N*N (dead after power -> Vp0)
  float* YAt = Mm + (size_t)N * N;              // N*N
  float* Xa  = YAt + (size_t)N * N;             // N*N fp32 ping
  float* Xb  = Xa + (size_t)N * N;              // N*N fp32 pong
  float* Vpx = Xb + (size_t)N * N;              // 3 * N*N (Vp1..Vp3)
  unsigned short* Zq = (unsigned short*)(Vpx + 3 * (size_t)N * N);  // N*N bf16
  unsigned short* Mh = Zq + (size_t)N * N;
  unsigned short* Ml = Mh + (size_t)N * N;
  float* vb    = (float*)(Ml + (size_t)N * N);  // 3*N
  float* stepP = vb + 3 * N;
  float* Vp0 = Mm;                      // alias: Mm dead after power phase
  float* Vp1 = Vpx;
  float* Vp2 = Vpx + (size_t)N * N;
  float* Vp3 = Vpx + 2 * (size_t)N * N;
  float* AnT = Vp1;                     // alias after FISTA loop (D*N)
  float* P   = Vp1 + (size_t)N * D;     // alias after FISTA loop (N*D)
  float* cosb = YAt;                    // alias after FISTA loop

  normalize_k<<<2 * N, 256, 0, stream>>>(fea1, fea2, Yn, An);
  gemm_nt<<<dim3(N / 64, N / 64), 256, 0, stream>>>(An, D, An, D, Mm, N, D);
  gemm_nt<<<dim3(N / 64, N / 64), 256, 0, stream>>>(Yn, D, An, D, YAt, N, D);
  split_k<<<(N * N) / 256, 256, 0, stream>>>(Mm, Mh, Ml);
  init_k<<<(N * N) / 256, 256, 0, stream>>>(Xa, Xb, Zq, vb);

  // power iteration (normalization folded into 1/8 scale; lambda_max ~5.8 < 8)
  float* pv = vb;
  float* pw = vb + N;
  for (int i = 0; i < PIT; ++i) {
    matvec_k<<<N / 4, 256, 0, stream>>>(Mm, pv, pw, 0.125f);
    float* t = pv; pv = pw; pw = t;
  }
  matvec_k<<<N / 4, 256, 0, stream>>>(Mm, pv, pw, 1.0f);
  rayleigh_k<<<1, 256, 0, stream>>>(pv, pw, stepP);

  float t = 1.0f, momPrev = 0.0f;
  float* Xcur = Xa;
  float* Xnext = Xb;
  for (int it = 0; it < NIT; ++it) {
    fista_gemm<<<1024, 256, 0, stream>>>(Zq, Mh, Ml, Vp0, Vp1, Vp2, Vp3);
    float tn = 0.5f * (1.0f + sqrtf(1.0f + 4.0f * t * t));
    float momCur = (t - 1.0f) / tn;
    t = tn;
    fista_update<<<N, 256, 0, stream>>>(Vp0, Vp1, Vp2, Vp3, YAt, stepP, Xcur,
                                        Xnext, Zq, momPrev, momCur);
    momPrev = momCur;
    float* tmp = Xcur; Xcur = Xnext; Xnext = tmp;
  }
  // final X is in Xcur

  transpose_k<<<dim3(D / 32, N / 32), dim3(32, 8), 0, stream>>>(An, AnT);
  gemm_nt<<<dim3(D / 64, N / 64), 256, 0, stream>>>(Xcur, N, AnT, N, P, D, N);
  cos_k<<<N, 128, 0, stream>>>(P, Yn, cosb);
  mean_k<<<1, 256, 0, stream>>>(cosb, (float*)d_out);
}